// Round 1
// baseline (322.033 us; speedup 1.0000x reference)
//
#include <hip/hip_runtime.h>
#include <math.h>

#define Bn 32
#define Gn 16
#define Hn 64
#define Wn 64
#define An 5
#define NCn 80
#define HWn 4096
#define CHn 86            // 6 + NUM_CLASSES
#define CHBn (An * CHn)   // 430 channels per batch

__device__ __constant__ float d_aw[5] = {1.3221f, 3.19275f, 5.05587f, 9.47112f, 11.2364f};
__device__ __constant__ float d_ah[5] = {1.73145f, 4.00944f, 8.09892f, 4.84053f, 10.0071f};
__device__ __constant__ float d_aa[5] = {0.0f, 0.3927f, 0.7854f, 1.1781f, 1.5708f};

__device__ __forceinline__ float sigmoidf_(float x) {
    return 1.0f / (1.0f + expf(-x));
}

// ws[0] = sum coord sq (masked)     -> *5/ (B*A*4*HW)
// ws[1] = sum conf sq (all + corr)  -> / (B*A*HW)
// ws[2] = sum class nll (masked)    -> *2 / 512
// ws[3] = sum theta smoothl1        -> *5 / 512
__global__ void yolo_main(const float* __restrict__ outp,
                          const float* __restrict__ gtb,
                          const int* __restrict__ gtc,
                          float* __restrict__ ws) {
    const int bid = blockIdx.x;
    if (bid < 640) {
        // ---- conf channel full sweep: sum sigmoid(x)^2 over (B, A, HW) ----
        // 640 blocks * 256 threads = 163840 threads, one float4 each
        // total float4s = B*A*HW/4 = 163840
        int t = bid * 256 + threadIdx.x;
        int hw4 = t & 1023;         // HW/4 = 1024 float4 per (b,a) row
        int ra  = t >> 10;          // 0..159
        int a   = ra % 5;
        int b   = ra / 5;
        const float4* p = (const float4*)(outp + (size_t)(b * CHBn + a * CHn + 4) * HWn);
        float4 v = p[hw4];
        float s0 = sigmoidf_(v.x);
        float s1 = sigmoidf_(v.y);
        float s2 = sigmoidf_(v.z);
        float s3 = sigmoidf_(v.w);
        float local = s0 * s0 + s1 * s1 + s2 * s2 + s3 * s3;
        // block reduce
        #pragma unroll
        for (int off = 32; off > 0; off >>= 1)
            local += __shfl_down(local, off, 64);
        __shared__ float smem[4];
        int lane = threadIdx.x & 63;
        int wv   = threadIdx.x >> 6;
        if (lane == 0) smem[wv] = local;
        __syncthreads();
        if (threadIdx.x == 0)
            atomicAdd(&ws[1], smem[0] + smem[1] + smem[2] + smem[3]);
    } else {
        // ---- per-ground-truth losses: blocks 640..641, one thread per gt ----
        int j = (bid - 640) * 256 + threadIdx.x;   // 0..511
        int b = j >> 4;
        int g = j & 15;
        const float* gt = gtb + (size_t)(b * Gn + g) * 5;
        float gx  = gt[0] * Wn;
        float gy  = gt[1] * Hn;
        float gw  = gt[2] * Wn;
        float gh  = gt[3] * Hn;
        float gth = gt[4] * 0.39269908169872414f;   // pi/8

        // best anchor by iou = cos(0.25*(gth - aa)); first index wins ties
        float best_iou = -1e30f;
        int best = 0;
        #pragma unroll
        for (int a = 0; a < 5; a++) {
            float iou = cosf(0.25f * (gth - d_aa[a]));
            if (iou > best_iou) { best_iou = iou; best = a; }
        }

        int gi = (int)gx; gi = gi < 0 ? 0 : (gi > Wn - 1 ? Wn - 1 : gi);
        int gj = (int)gy; gj = gj < 0 ? 0 : (gj > Hn - 1 ? Hn - 1 : gj);
        int cell = gj * Wn + gi;

        float tx  = gx - (float)gi;
        float ty  = gy - (float)gj;
        float tw  = logf(fmaxf(gw, 1.0f) / d_aw[best]);
        float th_ = logf(fmaxf(gh, 1.0f) / d_ah[best]);
        float tth = gth - d_aa[best];

        const float* base = outp + (size_t)(b * CHBn + best * CHn) * HWn + cell;
        float c0  = base[0];
        float c1  = base[HWn];
        float c2  = base[2 * HWn];
        float c3  = base[3 * HWn];
        float cf  = base[4 * HWn];
        float thv = base[5 * HWn];

        // coord
        float p0 = sigmoidf_(c0);
        float p1 = sigmoidf_(c1);
        float d0 = p0 - tx, d1 = p1 - ty, d2 = c2 - tw, d3 = c3 - th_;
        float coord = d0 * d0 + d1 * d1 + d2 * d2 + d3 * d3;

        // conf correction at object cell: replace (s*1)^2 with (5*(s-iou))^2
        float s  = sigmoidf_(cf);
        float dc = 5.0f * (s - best_iou);
        float confcorr = dc * dc - s * s;

        // theta smooth-l1
        float dth = fabsf(thv - tth);
        float sl  = dth < 1.0f ? 0.5f * dth * dth : dth - 0.5f;

        // class NLL: log_softmax over 80 logits (stride HW apart)
        float lg[80];
        #pragma unroll
        for (int c = 0; c < 80; c++) lg[c] = base[(6 + c) * HWn];
        float m = -1e30f;
        #pragma unroll
        for (int c = 0; c < 80; c++) m = fmaxf(m, lg[c]);
        float se = 0.0f;
        #pragma unroll
        for (int c = 0; c < 80; c++) se += expf(lg[c] - m);
        float lse = logf(se) + m;
        int tc = gtc[b * Gn + g];
        float nll = lse - lg[tc];

        atomicAdd(&ws[0], coord);
        atomicAdd(&ws[1], confcorr);
        atomicAdd(&ws[2], nll);
        atomicAdd(&ws[3], sl);
    }
}

__global__ void yolo_final(const float* __restrict__ ws, float* __restrict__ out5) {
    float coord = 5.0f * ws[0] / 2621440.0f;   // B*A*4*HW
    float conf  = ws[1] / 655360.0f;           // B*A*HW
    float cls   = 2.0f * ws[2] / 512.0f;       // CLASS_SCALE*2*sum/n, n=B*G
    float th    = 5.0f * ws[3] / 512.0f;
    out5[0] = coord + conf + cls + th;
    out5[1] = coord;
    out5[2] = conf;
    out5[3] = cls;
    out5[4] = th;
}

extern "C" void kernel_launch(void* const* d_in, const int* in_sizes, int n_in,
                              void* d_out, int out_size, void* d_ws, size_t ws_size,
                              hipStream_t stream) {
    const float* outp = (const float*)d_in[0];
    const float* gtb  = (const float*)d_in[1];
    const int*   gtc  = (const int*)d_in[2];
    float* out5 = (float*)d_out;
    float* ws   = (float*)d_ws;

    hipMemsetAsync(ws, 0, 4 * sizeof(float), stream);
    yolo_main<<<642, 256, 0, stream>>>(outp, gtb, gtc, ws);
    yolo_final<<<1, 1, 0, stream>>>(ws, out5);
}

// Round 2
// 257.701 us; speedup vs baseline: 1.2496x; 1.2496x over previous
//
#include <hip/hip_runtime.h>
#include <math.h>

#define Bn 32
#define Gn 16
#define Hn 64
#define Wn 64
#define An 5
#define NCn 80
#define HWn 4096
#define CHn 86            // 6 + NUM_CLASSES
#define CHBn (An * CHn)   // 430 channels per batch

// block layout: 0..159   = conf sweep, one (b,a) row each
//               160..287 = GT blocks, 4 waves/block, 1 wave per GT (512 GTs)
#define NCONF_BLK 160
#define NGT_BLK   128
#define NBLK      (NCONF_BLK + NGT_BLK)

__device__ __constant__ float d_aw[5] = {1.3221f, 3.19275f, 5.05587f, 9.47112f, 11.2364f};
__device__ __constant__ float d_ah[5] = {1.73145f, 4.00944f, 8.09892f, 4.84053f, 10.0071f};
__device__ __constant__ float d_aa[5] = {0.0f, 0.3927f, 0.7854f, 1.1781f, 1.5708f};

__device__ __forceinline__ float sigmoidf_(float x) {
    return 1.0f / (1.0f + expf(-x));
}

// slot[bid] = float4(coord_sum, conf_sum, nll_sum, smoothl1_sum)
__global__ __launch_bounds__(256) void yolo_main(const float* __restrict__ outp,
                                                 const float* __restrict__ gtb,
                                                 const int* __restrict__ gtc,
                                                 float4* __restrict__ slots) {
    const int bid  = blockIdx.x;
    const int tid  = threadIdx.x;
    const int lane = tid & 63;
    const int wv   = tid >> 6;
    __shared__ float4 smem[4];

    if (bid < NCONF_BLK) {
        // ---- conf channel sweep: one (b,a) row (4096 floats) per block ----
        int a = bid % 5;
        int b = bid / 5;
        const float4* p = (const float4*)(outp + (size_t)(b * CHBn + a * CHn + 4) * HWn);
        float local = 0.0f;
        #pragma unroll
        for (int k = 0; k < 4; k++) {
            float4 v = p[tid + 256 * k];
            float s0 = sigmoidf_(v.x), s1 = sigmoidf_(v.y);
            float s2 = sigmoidf_(v.z), s3 = sigmoidf_(v.w);
            local += s0 * s0 + s1 * s1 + s2 * s2 + s3 * s3;
        }
        #pragma unroll
        for (int m = 32; m > 0; m >>= 1)
            local += __shfl_xor(local, m, 64);
        if (lane == 0) smem[wv] = make_float4(0.f, local, 0.f, 0.f);
        __syncthreads();
        if (tid == 0) {
            float c = smem[0].y + smem[1].y + smem[2].y + smem[3].y;
            slots[bid] = make_float4(0.f, c, 0.f, 0.f);
        }
    } else {
        // ---- one wave per ground truth ----
        int j = (bid - NCONF_BLK) * 4 + wv;     // 0..511
        int b = j >> 4;
        int g = j & 15;
        const float* gt = gtb + (size_t)(b * Gn + g) * 5;
        float gx  = gt[0] * Wn;
        float gy  = gt[1] * Hn;
        float gw  = gt[2] * Wn;
        float gh  = gt[3] * Hn;
        float gth = gt[4] * 0.39269908169872414f;   // pi/8

        float best_iou = -1e30f;
        int best = 0;
        #pragma unroll
        for (int a = 0; a < 5; a++) {
            float iou = cosf(0.25f * (gth - d_aa[a]));
            if (iou > best_iou) { best_iou = iou; best = a; }
        }

        int gi = (int)gx; gi = gi < 0 ? 0 : (gi > Wn - 1 ? Wn - 1 : gi);
        int gj = (int)gy; gj = gj < 0 ? 0 : (gj > Hn - 1 ? Hn - 1 : gj);
        int cell = gj * Wn + gi;

        float tx  = gx - (float)gi;
        float ty  = gy - (float)gj;
        float tw  = logf(fmaxf(gw, 1.0f) / d_aw[best]);
        float th_ = logf(fmaxf(gh, 1.0f) / d_ah[best]);
        float tth = gth - d_aa[best];

        const float* base = outp + (size_t)(b * CHBn + best * CHn) * HWn + cell;

        // class logits: lane i -> class i; lanes 0..15 also class 64+i
        float lg0 = base[(6 + lane) * HWn];
        float lg1 = (lane < 16) ? base[(6 + 64 + lane) * HWn] : -1e30f;
        // head channels: lanes 0..5 load coord0..3, conf, theta
        float hv = (lane < 6) ? base[lane * HWn] : 0.0f;

        // wave max
        float m = fmaxf(lg0, lg1);
        #pragma unroll
        for (int s = 32; s > 0; s >>= 1)
            m = fmaxf(m, __shfl_xor(m, s, 64));
        // wave sum of exp
        float e = expf(lg0 - m) + ((lane < 16) ? expf(lg1 - m) : 0.0f);
        #pragma unroll
        for (int s = 32; s > 0; s >>= 1)
            e += __shfl_xor(e, s, 64);
        float lse = logf(e) + m;

        int tc = gtc[b * Gn + g];
        float ltc = (tc < 64) ? __shfl(lg0, tc, 64) : __shfl(lg1, tc - 64, 64);
        float nll = lse - ltc;

        float c0 = __shfl(hv, 0, 64), c1 = __shfl(hv, 1, 64);
        float c2 = __shfl(hv, 2, 64), c3 = __shfl(hv, 3, 64);
        float cf = __shfl(hv, 4, 64), thv = __shfl(hv, 5, 64);

        float p0 = sigmoidf_(c0);
        float p1 = sigmoidf_(c1);
        float d0 = p0 - tx, d1 = p1 - ty, d2 = c2 - tw, d3 = c3 - th_;
        float coord = d0 * d0 + d1 * d1 + d2 * d2 + d3 * d3;

        float s  = sigmoidf_(cf);
        float dc = 5.0f * (s - best_iou);
        float confcorr = dc * dc - s * s;

        float dth = fabsf(thv - tth);
        float sl  = dth < 1.0f ? 0.5f * dth * dth : dth - 0.5f;

        if (lane == 0) smem[wv] = make_float4(coord, confcorr, nll, sl);
        __syncthreads();
        if (tid == 0) {
            float4 r = smem[0];
            float4 q1 = smem[1], q2 = smem[2], q3 = smem[3];
            r.x += q1.x + q2.x + q3.x;
            r.y += q1.y + q2.y + q3.y;
            r.z += q1.z + q2.z + q3.z;
            r.w += q1.w + q2.w + q3.w;
            slots[bid] = r;
        }
    }
}

__global__ __launch_bounds__(256) void yolo_final(const float4* __restrict__ slots,
                                                  float* __restrict__ out5) {
    const int tid  = threadIdx.x;
    const int lane = tid & 63;
    const int wv   = tid >> 6;
    float4 acc = make_float4(0.f, 0.f, 0.f, 0.f);
    for (int i = tid; i < NBLK; i += 256) {
        float4 v = slots[i];
        acc.x += v.x; acc.y += v.y; acc.z += v.z; acc.w += v.w;
    }
    #pragma unroll
    for (int s = 32; s > 0; s >>= 1) {
        acc.x += __shfl_xor(acc.x, s, 64);
        acc.y += __shfl_xor(acc.y, s, 64);
        acc.z += __shfl_xor(acc.z, s, 64);
        acc.w += __shfl_xor(acc.w, s, 64);
    }
    __shared__ float4 smem[4];
    if (lane == 0) smem[wv] = acc;
    __syncthreads();
    if (tid == 0) {
        float4 r = smem[0];
        r.x += smem[1].x + smem[2].x + smem[3].x;
        r.y += smem[1].y + smem[2].y + smem[3].y;
        r.z += smem[1].z + smem[2].z + smem[3].z;
        r.w += smem[1].w + smem[2].w + smem[3].w;
        float coord = 5.0f * r.x / 2621440.0f;   // B*A*4*HW
        float conf  = r.y / 655360.0f;           // B*A*HW
        float cls   = 2.0f * r.z / 512.0f;
        float th    = 5.0f * r.w / 512.0f;
        out5[0] = coord + conf + cls + th;
        out5[1] = coord;
        out5[2] = conf;
        out5[3] = cls;
        out5[4] = th;
    }
}

extern "C" void kernel_launch(void* const* d_in, const int* in_sizes, int n_in,
                              void* d_out, int out_size, void* d_ws, size_t ws_size,
                              hipStream_t stream) {
    const float* outp = (const float*)d_in[0];
    const float* gtb  = (const float*)d_in[1];
    const int*   gtc  = (const int*)d_in[2];
    float* out5  = (float*)d_out;
    float4* slots = (float4*)d_ws;

    yolo_main<<<NBLK, 256, 0, stream>>>(outp, gtb, gtc, slots);
    yolo_final<<<1, 256, 0, stream>>>(slots, out5);
}